// Round 3
// baseline (921.739 us; speedup 1.0000x reference)
//
#include <hip/hip_runtime.h>
#include <stdint.h>

#define M_DIM 8192
#define N_DIM 11008
#define K_DIM 4096

// ---- main i8 GEMM geometry: 256x128 tile, 8 waves (wave tile 64x64), BK=64 ----
// 48 KB LDS/block + <=128 regs -> 2 blocks/CU (16 waves/CU): cross-block TLP
// covers the per-phase LDS/MFMA serialization and the vmcnt drains.
#define BM 256
#define BN 128
#define BK 64
#define KTILES (K_DIM / BK)   // 64

// ---- fallback bf16 geometry ----
#define FBM 128
#define FBN 128

typedef __attribute__((ext_vector_type(4))) int i32x4;
typedef __attribute__((ext_vector_type(8))) short bf16x8;
typedef __attribute__((ext_vector_type(4))) float f32x4;

__device__ __forceinline__ void async_cp16(const void* g, void* lds_uniform) {
  __builtin_amdgcn_global_load_lds(
      (__attribute__((address_space(1))) void*)(uintptr_t)g,
      (__attribute__((address_space(3))) void*)(uintptr_t)lds_uniform,
      16, 0, 0);
}

__device__ __forceinline__ unsigned short f2bf(float f) {
  unsigned int u = __float_as_uint(f);
  u += 0x7fffu + ((u >> 16) & 1u);
  return (unsigned short)(u >> 16);
}
__device__ __forceinline__ unsigned short i2bf(int v) {
  return (unsigned short)(__float_as_uint((float)v) >> 16);
}

__device__ __forceinline__ int pack4(int a, int b, int c, int d) {
  return (a & 0xFF) | ((b & 0xFF) << 8) | ((c & 0xFF) << 16) | ((d & 0xFF) << 24);
}

// one block per row: row absmax -> quantize to i8 with step = max/127
__global__ __launch_bounds__(256) void quant_x(const float* __restrict__ x,
                                               signed char* __restrict__ xq,
                                               float* __restrict__ row_step) {
  __shared__ float red[256];
  const unsigned int row = blockIdx.x, t = threadIdx.x;
  const float* xr = x + (size_t)row * K_DIM;
  float4 v[4];
#pragma unroll
  for (int j = 0; j < 4; ++j)
    v[j] = *(const float4*)(xr + j * 1024 + t * 4);

  float m = 0.f;
#pragma unroll
  for (int j = 0; j < 4; ++j) {
    m = fmaxf(m, fmaxf(fmaxf(fabsf(v[j].x), fabsf(v[j].y)),
                       fmaxf(fabsf(v[j].z), fabsf(v[j].w))));
  }
  red[t] = m;
  __syncthreads();
#pragma unroll
  for (int s = 128; s > 0; s >>= 1) {
    if (t < s) red[t] = fmaxf(red[t], red[t + s]);
    __syncthreads();
  }
  const float mx = red[0];
  const float r = (mx > 0.f) ? 127.0f / mx : 0.0f;
  if (t == 0) row_step[row] = (mx > 0.f) ? mx / 127.0f : 0.0f;

  int* out = (int*)(xq + (size_t)row * K_DIM);
#pragma unroll
  for (int j = 0; j < 4; ++j) {
    int q0 = __float2int_rn(v[j].x * r);
    int q1 = __float2int_rn(v[j].y * r);
    int q2 = __float2int_rn(v[j].z * r);
    int q3 = __float2int_rn(v[j].w * r);
    out[j * 256 + t] = pack4(q0, q1, q2, q3);
  }
}

// int32 weights {-1,0,1} -> i8 (exact)
__global__ __launch_bounds__(256) void quant_w(const int4* __restrict__ w,
                                               int* __restrict__ wq) {
  const size_t base = (size_t)blockIdx.x * 1024 + threadIdx.x;
#pragma unroll
  for (int j = 0; j < 4; ++j) {
    int4 a = w[base + j * 256];
    wq[base + j * 256] = pack4(a.x, a.y, a.z, a.w);
  }
}

// ---------------------------------------------------------------------------
// One K-tile (BK=64) : 2 phases x {ds_read subtile | stage | barrier | lgkm0 |
// 8 MFMA | barrier}.  Swizzle: 16B chunk c of row r lives at LDS slot
// c ^ (r&3) ^ ((r>>2)&3); global source pre-swizzled, global_load_lds dest
// linear, ds_read swizzled (both-sides rule).
// ---------------------------------------------------------------------------
__device__ __forceinline__ void ktile_iter(
    const signed char* Ab, const signed char* Bb,
    signed char* An, signed char* Bn, bool pf,
    i32x4 (&acc)[4][4],
    const signed char*& ag0, const signed char*& ag1, const signed char*& bg0,
    unsigned abase, unsigned bbase, unsigned ldsw)
{
  // B fragments for the whole K-tile (4 x b128), plus A mi 0-1
  i32x4 bfr[4];
#pragma unroll
  for (int ni = 0; ni < 4; ++ni)
    bfr[ni] = *(const i32x4*)(Bb + bbase + ni * 1024u);

  i32x4 afr[2];

  // ---------------- phase 0: mi 0-1 ----------------
#pragma unroll
  for (int mi = 0; mi < 2; ++mi)
    afr[mi] = *(const i32x4*)(Ab + abase + mi * 1024u);
  if (pf) {
    async_cp16(ag0, An + ldsw);            // A rows   0..127
    async_cp16(ag1, An + 8192 + ldsw);     // A rows 128..255
    async_cp16(bg0, Bn + ldsw);            // B rows   0..127
  }
  __builtin_amdgcn_s_barrier();
  asm volatile("s_waitcnt lgkmcnt(0)" ::: "memory");
  __builtin_amdgcn_sched_barrier(0);
  __builtin_amdgcn_s_setprio(1);
#pragma unroll
  for (int mi = 0; mi < 2; ++mi)
#pragma unroll
    for (int ni = 0; ni < 4; ++ni)
      acc[mi][ni] = __builtin_amdgcn_mfma_i32_16x16x64_i8(afr[mi], bfr[ni], acc[mi][ni], 0, 0, 0);
  __builtin_amdgcn_s_setprio(0);
  __builtin_amdgcn_s_barrier();

  // ---------------- phase 1: mi 2-3 (+ stage drain) ----------------
#pragma unroll
  for (int mi = 0; mi < 2; ++mi)
    afr[mi] = *(const i32x4*)(Ab + abase + (mi + 2) * 1024u);
  __builtin_amdgcn_s_barrier();
  asm volatile("s_waitcnt lgkmcnt(0)" ::: "memory");
  __builtin_amdgcn_sched_barrier(0);
  __builtin_amdgcn_s_setprio(1);
#pragma unroll
  for (int mi = 0; mi < 2; ++mi)
#pragma unroll
    for (int ni = 0; ni < 4; ++ni)
      acc[mi + 2][ni] = __builtin_amdgcn_mfma_i32_16x16x64_i8(afr[mi], bfr[ni], acc[mi + 2][ni], 0, 0, 0);
  __builtin_amdgcn_s_setprio(0);
  asm volatile("s_waitcnt vmcnt(0)" ::: "memory");
  __builtin_amdgcn_s_barrier();

  ag0 += BK; ag1 += BK; bg0 += BK;
}

// ---- main GEMM: A (MxK i8), B (NxK i8), C = (A*B^T)_i32 * (row_step*w_scale) + bias ----
__global__ __launch_bounds__(512, 4) void gemm_i8(
    const signed char* __restrict__ A,
    const signed char* __restrict__ B,
    const float* __restrict__ row_step,
    const float* __restrict__ bias,
    const float* __restrict__ scale_p,
    float* __restrict__ C)
{
  __shared__ __align__(16) signed char As[2][BM * BK];   // 2 x 16 KB
  __shared__ __align__(16) signed char Bs[2][BN * BK];   // 2 x  8 KB  (48 KB total)

  const unsigned t = threadIdx.x;
  const unsigned lane = t & 63u;
  const unsigned wave = t >> 6;

  // T1: bijective XCD-chunked swizzle (nwg = 86*32 = 2752, divisible by 8)
  const unsigned nbx = gridDim.x;                 // 86
  unsigned bid = blockIdx.y * nbx + blockIdx.x;
  const unsigned cpx = (nbx * gridDim.y) >> 3;    // 344
  bid = (bid & 7u) * cpx + (bid >> 3);
  const unsigned n0 = (bid % nbx) * BN;
  const unsigned m0 = (bid / nbx) * BM;

  const unsigned wm = (wave >> 1) * 64u;   // 4 M wave-rows
  const unsigned wn = (wave & 1u) * 64u;   // 2 N wave-cols
  const unsigned fr = lane & 15u;
  const unsigned fq = lane >> 4;

  // staging: thread t -> row t>>2 (per 128-row group), LDS slot t&3 (linear
  // dest); global source chunk = (t&3) ^ (r&3) ^ ((r>>2)&3)
  const unsigned rst = t >> 2;
  const unsigned c_src = (t & 3u) ^ ((t >> 2) & 3u) ^ ((t >> 4) & 3u);
  const signed char* ag0 = A + (size_t)(m0 + rst) * K_DIM + c_src * 16u;
  const signed char* ag1 = A + (size_t)(m0 + 128 + rst) * K_DIM + c_src * 16u;
  const signed char* bg0 = B + (size_t)(n0 + rst) * K_DIM + c_src * 16u;
  const unsigned ldsw = (t & 448u) * 16u;   // wave-uniform base (HW adds lane*16)

  // fragment read: row = w?+mi*16+fr, chunk fq -> slot fq ^ (fr&3) ^ (fr>>2)
  const unsigned swz = (fq ^ (fr & 3u) ^ (fr >> 2)) << 4;
  const unsigned abase = (wm + fr) * BK + swz;
  const unsigned bbase = (wn + fr) * BK + swz;

  i32x4 acc[4][4];
#pragma unroll
  for (int i = 0; i < 4; ++i)
#pragma unroll
    for (int j = 0; j < 4; ++j)
      acc[i][j] = (i32x4){0, 0, 0, 0};

  // prologue: stage K-tile 0 into buffer 0
  async_cp16(ag0, As[0] + ldsw);
  async_cp16(ag1, As[0] + 8192 + ldsw);
  async_cp16(bg0, Bs[0] + ldsw);
  ag0 += BK; ag1 += BK; bg0 += BK;
  asm volatile("s_waitcnt vmcnt(0)" ::: "memory");
  __builtin_amdgcn_s_barrier();

  for (int kt = 0; kt < KTILES; kt += 2) {
    ktile_iter(As[0], Bs[0], As[1], Bs[1], true,
               acc, ag0, ag1, bg0, abase, bbase, ldsw);
    ktile_iter(As[1], Bs[1], As[0], Bs[0], (kt + 2) < KTILES,
               acc, ag0, ag1, bg0, abase, bbase, ldsw);
  }

  // epilogue: dequant + bias; C layout col = fr, row = fq*4 + r (verified).
  // Nontemporal stores: C is never re-read -> don't evict A/B from L2/L3.
  const float ws = scale_p[0];
  float bb[4];
#pragma unroll
  for (int ni = 0; ni < 4; ++ni)
    bb[ni] = bias[n0 + wn + ni * 16 + fr];

#pragma unroll
  for (int mi = 0; mi < 4; ++mi) {
    const unsigned mg = m0 + wm + mi * 16 + fq * 4;
    const float rs0 = row_step[mg + 0] * ws;
    const float rs1 = row_step[mg + 1] * ws;
    const float rs2 = row_step[mg + 2] * ws;
    const float rs3 = row_step[mg + 3] * ws;
#pragma unroll
    for (int ni = 0; ni < 4; ++ni) {
      const unsigned ng = n0 + wn + ni * 16 + fr;
      i32x4 v = acc[mi][ni];
      float* cp = C + (size_t)mg * N_DIM + ng;
      __builtin_nontemporal_store((float)v[0] * rs0 + bb[ni], cp);
      __builtin_nontemporal_store((float)v[1] * rs1 + bb[ni], cp + (size_t)1 * N_DIM);
      __builtin_nontemporal_store((float)v[2] * rs2 + bb[ni], cp + (size_t)2 * N_DIM);
      __builtin_nontemporal_store((float)v[3] * rs3 + bb[ni], cp + (size_t)3 * N_DIM);
    }
  }
}

// ---- fallback (ws too small): bf16 fused convert-in-staging (correct, slower) ----
__global__ __launch_bounds__(256) void gemm_fused(
    const float* __restrict__ X,
    const int* __restrict__ W,
    const float* __restrict__ bias,
    const float* __restrict__ scale_p,
    float* __restrict__ C)
{
  __shared__ __align__(16) unsigned short As[FBM * 32];
  __shared__ __align__(16) unsigned short Bs[FBN * 32];

  const unsigned int t = threadIdx.x;
  const unsigned int n0 = blockIdx.x * FBN;
  const unsigned int m0 = blockIdx.y * FBM;
  const unsigned int lane = t & 63u;
  const unsigned int wave = t >> 6;
  const unsigned int wm = (wave >> 1) * 64u;
  const unsigned int wn = (wave & 1u) * 64u;
  const unsigned int fr = lane & 15u;
  const unsigned int fq = lane >> 4;

  const unsigned short* afp = As + (wm + fr) * 32 + fq * 8u;
  const unsigned short* bfp = Bs + (wn + fr) * 32 + fq * 8u;
  const unsigned int brow = t >> 1, bcol = (t & 1u) * 16u;

  f32x4 acc[4][4];
#pragma unroll
  for (int i = 0; i < 4; ++i)
#pragma unroll
    for (int j = 0; j < 4; ++j)
      acc[i][j] = (f32x4){0.f, 0.f, 0.f, 0.f};

  for (int kt = 0; kt < K_DIM; kt += 32) {
#pragma unroll
    for (int i = 0; i < 4; ++i) {
      unsigned int c = t + i * 256;
      unsigned int row = c >> 3, col = (c & 7u) * 4u;
      float4 v = *(const float4*)(X + (size_t)(m0 + row) * K_DIM + kt + col);
      ushort4 o;
      o.x = f2bf(v.x); o.y = f2bf(v.y); o.z = f2bf(v.z); o.w = f2bf(v.w);
      *(ushort4*)(As + row * 32 + col) = o;
    }
    {
      const int* wp = W + (size_t)(n0 + brow) * K_DIM + kt + bcol;
      int4 a = *(const int4*)(wp);
      int4 b = *(const int4*)(wp + 4);
      int4 c = *(const int4*)(wp + 8);
      int4 d = *(const int4*)(wp + 12);
      uint4 o0, o1;
      o0.x = (unsigned int)i2bf(a.x) | ((unsigned int)i2bf(a.y) << 16);
      o0.y = (unsigned int)i2bf(a.z) | ((unsigned int)i2bf(a.w) << 16);
      o0.z = (unsigned int)i2bf(b.x) | ((unsigned int)i2bf(b.y) << 16);
      o0.w = (unsigned int)i2bf(b.z) | ((unsigned int)i2bf(b.w) << 16);
      o1.x = (unsigned int)i2bf(c.x) | ((unsigned int)i2bf(c.y) << 16);
      o1.y = (unsigned int)i2bf(c.z) | ((unsigned int)i2bf(c.w) << 16);
      o1.z = (unsigned int)i2bf(d.x) | ((unsigned int)i2bf(d.y) << 16);
      o1.w = (unsigned int)i2bf(d.z) | ((unsigned int)i2bf(d.w) << 16);
      *(uint4*)(Bs + brow * 32 + bcol)     = o0;
      *(uint4*)(Bs + brow * 32 + bcol + 8) = o1;
    }
    __syncthreads();

    bf16x8 af[4], bgf[4];
#pragma unroll
    for (int mi = 0; mi < 4; ++mi)
      af[mi] = *(const bf16x8*)(afp + mi * 16 * 32);
#pragma unroll
    for (int ni = 0; ni < 4; ++ni)
      bgf[ni] = *(const bf16x8*)(bfp + ni * 16 * 32);
#pragma unroll
    for (int mi = 0; mi < 4; ++mi)
#pragma unroll
      for (int ni = 0; ni < 4; ++ni)
        acc[mi][ni] = __builtin_amdgcn_mfma_f32_16x16x32_bf16(af[mi], bgf[ni], acc[mi][ni], 0, 0, 0);
    __syncthreads();
  }

  const float scale = scale_p[0];
#pragma unroll
  for (int ni = 0; ni < 4; ++ni) {
    const unsigned int ng = n0 + wn + ni * 16 + fr;
    const float bbv = bias[ng];
#pragma unroll
    for (int mi = 0; mi < 4; ++mi) {
      const unsigned int mg = m0 + wm + mi * 16 + fq * 4;
      f32x4 v = acc[mi][ni];
#pragma unroll
      for (int r = 0; r < 4; ++r)
        C[(size_t)(mg + r) * N_DIM + ng] = v[r] * scale + bbv;
    }
  }
}

extern "C" void kernel_launch(void* const* d_in, const int* in_sizes, int n_in,
                              void* d_out, int out_size, void* d_ws, size_t ws_size,
                              hipStream_t stream) {
  const float* x     = (const float*)d_in[0];
  const int*   wq    = (const int*)d_in[1];    // integer inputs arrive as int32
  const float* scale = (const float*)d_in[2];
  const float* bias  = (const float*)d_in[3];
  float* out         = (float*)d_out;

  const size_t xq_bytes = (size_t)M_DIM * K_DIM;       // 33.5 MB
  const size_t wq_bytes = (size_t)N_DIM * K_DIM;       // 45.1 MB
  const size_t rs_bytes = (size_t)M_DIM * sizeof(float);
  const size_t need = xq_bytes + wq_bytes + rs_bytes;

  if (ws_size >= need) {
    signed char* xqp = (signed char*)d_ws;
    signed char* wqp = xqp + xq_bytes;
    float* row_step  = (float*)(wqp + wq_bytes);

    dim3 grid(N_DIM / BN, M_DIM / BM);  // 86 x 32
    quant_x<<<M_DIM, 256, 0, stream>>>(x, xqp, row_step);
    quant_w<<<(unsigned)(wq_bytes / (16 * 256)), 256, 0, stream>>>(
        (const int4*)wq, (int*)wqp);
    gemm_i8<<<grid, 512, 0, stream>>>(xqp, wqp, row_step, bias, scale, out);
  } else {
    dim3 fgrid(N_DIM / FBN, M_DIM / FBM);  // 86 x 64
    gemm_fused<<<fgrid, 256, 0, stream>>>(x, wq, bias, scale, out);
  }
}